// Round 2
// baseline (401.811 us; speedup 1.0000x reference)
//
#include <hip/hip_runtime.h>
#include <hip/hip_bf16.h>
#include <math.h>

// Problem constants (from reference): B=8, S=4096, D=2048, E=64, TOP_K=2
#define BB 8
#define SS 4096
#define DD 2048
#define EE 64
#define NCHUNK 64                      // S split into 64 chunks of 64 rows
#define ROWS_PER_CHUNK (SS / NCHUNK)   // 64

// Kernel 1: partial column sums of x over S-chunks.
// grid = BB * NCHUNK * 2 = 1024 blocks (4 blocks/CU), 256 threads.
// Each block: batch b, S-chunk c, half-of-D h. Thread t handles 4 consecutive
// d's via float4 (coalesced 16B/lane, 1KB/wave-instruction).
// 4 independent accumulators break the serial add chain so the compiler can
// keep >=16 loads in flight per wave (HBM latency ~900cyc needs ~9KB/CU).
__global__ void mean_partial_kernel(const float* __restrict__ x,
                                    float* __restrict__ partial) {
    int blk   = blockIdx.x;
    int h     = blk & 1;                  // which half of D
    int c     = (blk >> 1) & (NCHUNK - 1);
    int b     = blk >> 7;                 // 1024 / 128 = 8 batches
    int d     = h * (DD / 2) + threadIdx.x * 4;

    const float4* xp = (const float4*)(x + (size_t)b * SS * DD
                                         + (size_t)c * ROWS_PER_CHUNK * DD
                                         + d);
    float4 a0 = make_float4(0.f, 0.f, 0.f, 0.f);
    float4 a1 = make_float4(0.f, 0.f, 0.f, 0.f);
    float4 a2 = make_float4(0.f, 0.f, 0.f, 0.f);
    float4 a3 = make_float4(0.f, 0.f, 0.f, 0.f);
    const size_t rs = DD / 4;             // float4 row stride
    #pragma unroll 4
    for (int r = 0; r < ROWS_PER_CHUNK; r += 4) {
        float4 v0 = xp[(size_t)(r + 0) * rs];
        float4 v1 = xp[(size_t)(r + 1) * rs];
        float4 v2 = xp[(size_t)(r + 2) * rs];
        float4 v3 = xp[(size_t)(r + 3) * rs];
        a0.x += v0.x; a0.y += v0.y; a0.z += v0.z; a0.w += v0.w;
        a1.x += v1.x; a1.y += v1.y; a1.z += v1.z; a1.w += v1.w;
        a2.x += v2.x; a2.y += v2.y; a2.z += v2.z; a2.w += v2.w;
        a3.x += v3.x; a3.y += v3.y; a3.z += v3.z; a3.w += v3.w;
    }
    float4 acc;
    acc.x = (a0.x + a1.x) + (a2.x + a3.x);
    acc.y = (a0.y + a1.y) + (a2.y + a3.y);
    acc.z = (a0.z + a1.z) + (a2.z + a3.z);
    acc.w = (a0.w + a1.w) + (a2.w + a3.w);
    float4* pp = (float4*)(partial + ((size_t)c * BB + b) * DD + d);
    *pp = acc;
}

// Kernel 2: per-batch: reduce chunk partials -> x_flat (mean), GEMV vs W,
// add bias, top-2 + softmax. grid = 8 blocks, 256 threads.
__global__ void gate_kernel(const float* __restrict__ partial,
                            const float* __restrict__ W,
                            const float* __restrict__ bias,
                            float* __restrict__ out) {
    __shared__ float xs[DD];        // 8 KB mean-pooled features
    __shared__ float lred[4][EE];   // quarter-D partial dots
    __shared__ float logits[EE];

    int b   = blockIdx.x;
    int tid = threadIdx.x;

    // Phase A: reduce NCHUNK chunk partials, divide by S
    for (int d = tid; d < DD; d += 256) {
        float s = 0.f;
        #pragma unroll 8
        for (int c = 0; c < NCHUNK; ++c)
            s += partial[((size_t)c * BB + b) * DD + d];
        xs[d] = s * (1.0f / SS);
    }
    __syncthreads();

    // Phase B: logits. thread -> (expert e = tid&63, quarter q = tid>>6)
    int e = tid & 63;
    int q = tid >> 6;
    const int QD = DD / 4;          // 512
    const float* wp = W + (size_t)e * DD + q * QD;
    const float* xq = xs + q * QD;
    float acc = 0.f;
    #pragma unroll 4
    for (int d = 0; d < QD; ++d) acc += xq[d] * wp[d];
    lred[q][e] = acc;
    __syncthreads();

    if (tid < EE) {
        logits[tid] = lred[0][tid] + lred[1][tid] + lred[2][tid] + lred[3][tid]
                      + bias[tid];
    }
    __syncthreads();

    // Phase D: top-2 (stable: lowest index wins ties, matching lax.top_k),
    // then softmax over the two kept logits.
    if (tid == 0) {
        float m1 = -INFINITY, m2 = -INFINITY;
        int i1 = 0, i2 = 0;
        for (int i = 0; i < EE; ++i) {
            float v = logits[i];
            if (v > m1) { m2 = m1; i2 = i1; m1 = v; i1 = i; }
            else if (v > m2) { m2 = v; i2 = i; }
        }
        float e2 = expf(m2 - m1);
        float inv = 1.0f / (1.0f + e2);
        // outputs concatenated flat: weights [8,2] then indices [8,2]
        out[b * 2 + 0] = inv;
        out[b * 2 + 1] = e2 * inv;
        out[2 * BB + b * 2 + 0] = (float)i1;
        out[2 * BB + b * 2 + 1] = (float)i2;
    }
}

extern "C" void kernel_launch(void* const* d_in, const int* in_sizes, int n_in,
                              void* d_out, int out_size, void* d_ws, size_t ws_size,
                              hipStream_t stream) {
    const float* x  = (const float*)d_in[0];   // [8, 4096, 2048]
    const float* W  = (const float*)d_in[1];   // [64, 2048]
    const float* bb = (const float*)d_in[2];   // [64]
    float* out      = (float*)d_out;           // 32 floats: weights(16) + indices(16)
    float* partial  = (float*)d_ws;            // NCHUNK*B*D floats = 4 MB

    mean_partial_kernel<<<BB * NCHUNK * 2, 256, 0, stream>>>(x, partial);
    gate_kernel<<<BB, 256, 0, stream>>>(partial, W, bb, out);
}

// Round 3
// 376.926 us; speedup vs baseline: 1.0660x; 1.0660x over previous
//
#include <hip/hip_runtime.h>
#include <hip/hip_bf16.h>
#include <math.h>

// Problem constants (from reference): B=8, S=4096, D=2048, E=64, TOP_K=2
#define BB 8
#define SS 4096
#define DD 2048
#define EE 64
#define NCHUNK 64                      // S split into 64 chunks
#define ROWS (SS / NCHUNK)             // 64 rows per chunk
#define NSLICE (NCHUNK * 2)            // 128 logit-partial slices per batch

// Kernel 1 (fused): stream x, accumulate column sums for a (b, S-chunk,
// half-D) tile, then immediately dot against the matching W slice to emit
// 64 partial logits. Output: plogit[blk][e], blk = b*128 + c*2 + h.
// grid = BB*NCHUNK*2 = 1024 blocks (4 blocks/CU, 16 waves/CU), 256 threads.
// x reads: coalesced float4 (16B/lane). W slice (256 KB/block) is L2-hot
// (W total = 512 KB). Partial-logit output is 256 KB total vs 8 MB of
// column partials in the unfused version.
__global__ void __launch_bounds__(256, 4)
fused_stream_kernel(const float* __restrict__ x,
                    const float* __restrict__ W,
                    float* __restrict__ plogit) {
    __shared__ float xs[DD / 2];     // 4 KB: this block's column sums
    __shared__ float lred[4][EE];    // 1 KB: quarter partial dots

    int blk = blockIdx.x;
    int h   = blk & 1;                    // which half of D
    int c   = (blk >> 1) & (NCHUNK - 1);
    int b   = blk >> 7;                   // 1024/128 = 8 batches
    int tid = threadIdx.x;
    int d   = h * (DD / 2) + tid * 4;

    // Phase A: column sums over ROWS rows (4 independent accumulators).
    const float4* xp = (const float4*)(x + (size_t)b * SS * DD
                                         + (size_t)c * ROWS * DD + d);
    float4 a0 = make_float4(0.f, 0.f, 0.f, 0.f);
    float4 a1 = make_float4(0.f, 0.f, 0.f, 0.f);
    float4 a2 = make_float4(0.f, 0.f, 0.f, 0.f);
    float4 a3 = make_float4(0.f, 0.f, 0.f, 0.f);
    const size_t rs = DD / 4;             // float4 row stride
    #pragma unroll 4
    for (int r = 0; r < ROWS; r += 4) {
        float4 v0 = xp[(size_t)(r + 0) * rs];
        float4 v1 = xp[(size_t)(r + 1) * rs];
        float4 v2 = xp[(size_t)(r + 2) * rs];
        float4 v3 = xp[(size_t)(r + 3) * rs];
        a0.x += v0.x; a0.y += v0.y; a0.z += v0.z; a0.w += v0.w;
        a1.x += v1.x; a1.y += v1.y; a1.z += v1.z; a1.w += v1.w;
        a2.x += v2.x; a2.y += v2.y; a2.z += v2.z; a2.w += v2.w;
        a3.x += v3.x; a3.y += v3.y; a3.z += v3.z; a3.w += v3.w;
    }
    float4 acc;
    acc.x = (a0.x + a1.x) + (a2.x + a3.x);
    acc.y = (a0.y + a1.y) + (a2.y + a3.y);
    acc.z = (a0.z + a1.z) + (a2.z + a3.z);
    acc.w = (a0.w + a1.w) + (a2.w + a3.w);
    ((float4*)xs)[tid] = acc;
    __syncthreads();

    // Phase B: partial logits for this d-span. thread -> (expert e, quarter q)
    int e = tid & 63;
    int q = tid >> 6;
    const int QF4 = (DD / 2 / 4) / 4;     // 64 float4s per quarter-span
    const float4* wp = (const float4*)(W + (size_t)e * DD
                                         + h * (DD / 2) + q * (QF4 * 4));
    const float4* xq = (const float4*)(xs + q * (QF4 * 4));
    float dot = 0.f;
    #pragma unroll 8
    for (int i = 0; i < QF4; ++i) {
        float4 wv = wp[i];
        float4 xv = xq[i];
        dot += wv.x * xv.x + wv.y * xv.y + wv.z * xv.z + wv.w * xv.w;
    }
    lred[q][e] = dot;
    __syncthreads();

    if (tid < EE) {
        plogit[(size_t)blk * EE + tid] =
            lred[0][tid] + lred[1][tid] + lred[2][tid] + lred[3][tid];
    }
}

// Kernel 2: per-batch reduce the 128 logit-partial slices, scale by 1/S,
// add bias, top-2 + softmax. grid = 8 blocks, 256 threads.
__global__ void gate_kernel(const float* __restrict__ plogit,
                            const float* __restrict__ bias,
                            float* __restrict__ out) {
    __shared__ float lred[4][EE];
    __shared__ float logits[EE];

    int b   = blockIdx.x;
    int tid = threadIdx.x;
    int e   = tid & 63;
    int g   = tid >> 6;                   // group of 32 slices

    float s = 0.f;
    #pragma unroll 8
    for (int j = g * (NSLICE / 4); j < (g + 1) * (NSLICE / 4); ++j)
        s += plogit[((size_t)b * NSLICE + j) * EE + e];
    lred[g][e] = s;
    __syncthreads();

    if (tid < EE) {
        logits[tid] = (lred[0][tid] + lred[1][tid] + lred[2][tid] + lred[3][tid])
                      * (1.0f / SS) + bias[tid];
    }
    __syncthreads();

    // top-2 (stable: lowest index wins ties, matching lax.top_k) + softmax
    if (tid == 0) {
        float m1 = -INFINITY, m2 = -INFINITY;
        int i1 = 0, i2 = 0;
        for (int i = 0; i < EE; ++i) {
            float v = logits[i];
            if (v > m1) { m2 = m1; i2 = i1; m1 = v; i1 = i; }
            else if (v > m2) { m2 = v; i2 = i; }
        }
        float e2 = expf(m2 - m1);
        float inv = 1.0f / (1.0f + e2);
        // outputs concatenated flat: weights [8,2] then indices [8,2]
        out[b * 2 + 0] = inv;
        out[b * 2 + 1] = e2 * inv;
        out[2 * BB + b * 2 + 0] = (float)i1;
        out[2 * BB + b * 2 + 1] = (float)i2;
    }
}

extern "C" void kernel_launch(void* const* d_in, const int* in_sizes, int n_in,
                              void* d_out, int out_size, void* d_ws, size_t ws_size,
                              hipStream_t stream) {
    const float* x  = (const float*)d_in[0];   // [8, 4096, 2048]
    const float* W  = (const float*)d_in[1];   // [64, 2048]
    const float* bb = (const float*)d_in[2];   // [64]
    float* out      = (float*)d_out;           // 32 floats: weights(16) + indices(16)
    float* plogit   = (float*)d_ws;            // 1024*64 floats = 256 KB

    fused_stream_kernel<<<BB * NCHUNK * 2, 256, 0, stream>>>(x, W, plogit);
    gate_kernel<<<BB, 256, 0, stream>>>(plogit, bb, out);
}